// Round 9
// baseline (414.510 us; speedup 1.0000x reference)
//
#include <hip/hip_runtime.h>

#define DN 384
#define DS 512
#define DMSA 64
#define DH 32
#define DP 128

typedef __bf16 bf16x8 __attribute__((ext_vector_type(8)));
typedef __bf16 bf16x4 __attribute__((ext_vector_type(4)));
typedef float f32x4 __attribute__((ext_vector_type(4)));

// ws layout (bytes)
#define OFF_BT  12582912u
#define OFF_WT  25165824u   // wt bf16 [p 128][k' 1024] = 256KB
#define OFF_INV 25427968u
#define OFF_SMF 25428224u
#define OFF_MKF 25430272u

__device__ __forceinline__ void async16(const void* g, void* l) {
  __builtin_amdgcn_global_load_lds((const __attribute__((address_space(1))) unsigned*)g,
                                   (__attribute__((address_space(3))) unsigned*)l, 16, 0, 0);
}

// ---------------------------------------------------------------------------
// prep: masks, 1/num_msa, w_out -> wt [p][k'=e*32+d].
// ---------------------------------------------------------------------------
__global__ __launch_bounds__(128) void prep_kernel(const void* __restrict__ mask_raw,
                                                   const void* __restrict__ msa_mask_raw,
                                                   const float* __restrict__ w_out,
                                                   __bf16* __restrict__ wt,
                                                   float* __restrict__ invp,
                                                   float* __restrict__ smf,
                                                   float* __restrict__ mkf) {
  const int blk = blockIdx.x;
  const int tid = threadIdx.x;
  if (blk == 0) {
    __shared__ int sh[128];
    const unsigned int* u = (const unsigned int*)msa_mask_raw;
    int bad = (u[tid] > 1u) ? 1 : 0;
    sh[tid] = bad;
    __syncthreads();
    for (int off = 64; off > 0; off >>= 1) {
      if (tid < off) sh[tid] |= sh[tid + off];
      __syncthreads();
    }
    const int int_mode = (sh[0] == 0);
    __syncthreads();
    int cnt = 0;
    for (int q = tid; q < DS; q += 128) {
      float v;
      if (int_mode) v = (((const int*)msa_mask_raw)[q] != 0) ? 1.f : 0.f;
      else          v = (((const unsigned char*)msa_mask_raw)[q] != 0) ? 1.f : 0.f;
      smf[q] = v;
      cnt += (v != 0.f) ? 1 : 0;
    }
    sh[tid] = cnt;
    __syncthreads();
    for (int off = 64; off > 0; off >>= 1) {
      if (tid < off) sh[tid] += sh[tid + off];
      __syncthreads();
    }
    if (tid == 0) {
      float num = (float)sh[0];
      if (num < 1e-5f) num = 1e-5f;
      invp[0] = 1.0f / num;
    }
  } else if (blk == 1) {
    __shared__ int sh[128];
    const unsigned int* u = (const unsigned int*)mask_raw;
    int bad = 0;
    if (tid < 96) bad = (u[tid] > 1u) ? 1 : 0;
    sh[tid] = bad;
    __syncthreads();
    for (int off = 64; off > 0; off >>= 1) {
      if (tid < off) sh[tid] |= sh[tid + off];
      __syncthreads();
    }
    const int int_mode = (sh[0] == 0);
    __syncthreads();
    for (int q = tid; q < DN; q += 128) {
      float v;
      if (int_mode) v = (((const int*)mask_raw)[q] != 0) ? 1.f : 0.f;
      else          v = (((const unsigned char*)mask_raw)[q] != 0) ? 1.f : 0.f;
      mkf[q] = v;
    }
  } else {
    const int kw = blk - 2;                      // k = d*32+e
    const int p = tid;                           // 0..127
    const int kp = (kw & 31) * 32 + (kw >> 5);   // k' = e*32+d
    wt[(size_t)p * 1024 + kp] = (__bf16)w_out[(size_t)kw * DP + p];
  }
}

// ---------------------------------------------------------------------------
// ln_proj: LN(64) -> x@w_hidden (LDS-broadcast weights) -> mask/scale ->
// at/bt [n*32+c][s] bf16.
// ---------------------------------------------------------------------------
__global__ __launch_bounds__(256) void ln_proj_kernel(const float* __restrict__ msa,
                                                      const float* __restrict__ gamma,
                                                      const float* __restrict__ beta,
                                                      const float* __restrict__ w_hidden,
                                                      const float* __restrict__ invp,
                                                      const float* __restrict__ smf,
                                                      __bf16* __restrict__ at,
                                                      __bf16* __restrict__ bt) {
  __shared__ float wl[DMSA * 2 * DH];
  __shared__ float gl[DMSA], bl[DMSA];
  const int tid = threadIdx.x;
  for (int q = tid; q < DMSA * 2 * DH; q += 256) wl[q] = w_hidden[q];
  if (tid < DMSA) { gl[tid] = gamma[tid]; bl[tid] = beta[tid]; }
  __syncthreads();

  const int p = blockIdx.x * 256 + tid;
  const int n = p >> 9;
  const int s = p & 511;

  const float* mp = msa + ((size_t)s * DN + n) * DMSA;
  float x[64];
  float sum = 0.f, sq = 0.f;
#pragma unroll
  for (int q = 0; q < 16; ++q) {
    float4 v = ((const float4*)mp)[q];
    x[4 * q + 0] = v.x; x[4 * q + 1] = v.y; x[4 * q + 2] = v.z; x[4 * q + 3] = v.w;
    sum += v.x + v.y + v.z + v.w;
    sq  += v.x * v.x + v.y * v.y + v.z * v.z + v.w * v.w;
  }
  const float mu = sum * (1.f / 64.f);
  const float var = sq * (1.f / 64.f) - mu * mu;
  const float rstd = rsqrtf(var + 1e-5f);
#pragma unroll
  for (int d = 0; d < 64; ++d) x[d] = (x[d] - mu) * rstd * gl[d] + bl[d];

  const float sm = smf[s];
  const float sa = sm * invp[0];

  const size_t outbase = ((size_t)n * DH) * DS + s;
  for (int c = 0; c < DH; ++c) {
    float ha = 0.f, hb = 0.f;
#pragma unroll
    for (int d = 0; d < 64; ++d) {
      ha += x[d] * wl[d * 64 + c];
      hb += x[d] * wl[d * 64 + DH + c];
    }
    at[outbase + (size_t)c * DS] = (__bf16)(ha * sa);
    bt[outbase + (size_t)c * DS] = (__bf16)(hb * sm);
  }
}

// ---------------------------------------------------------------------------
// fused: 128x128 tile, 256 threads (4 waves, 64x64/wave), BK=64 dbuf = 64KB
// LDS -> 2 blocks/CU (occupancy covers stalls). Coarse loop: stage-early ->
// conflict-free swizzled ds_reads -> 32 MFMA -> vmcnt(0)+barrier. Then
// op->LDS [16][2064] (aliased) -> GEMM2 16x128xK1024 (broadcast a2 reads,
// rolling wt prefetch) -> pair_mask + b_out epilogue.
// ---------------------------------------------------------------------------
__global__ __launch_bounds__(256, 2) void fused_kernel(const __bf16* __restrict__ at,
                                                       const __bf16* __restrict__ bt,
                                                       const __bf16* __restrict__ wt,
                                                       const float* __restrict__ mkf,
                                                       const float* __restrict__ b_out,
                                                       float* __restrict__ out) {
  // dbuf: 2 slots x (A 16KB + B 16KB) = 64KB; aliased opl 16x2064B = 33KB
  __shared__ __align__(128) char smem[65536];

  const int tid = threadIdx.x;
  const int l = tid & 63, w = tid >> 6;
  const int lr = l & 15, lk = l >> 4;
  const int wr = w >> 1, wc = w & 1;

  // XCD-aware swizzle: 144 supertiles of 8x8 blocks on the 96x96 grid.
  const int orig = blockIdx.x;
  const int xcd = orig & 7, sidx = orig >> 3;        // sidx 0..1151
  const int st = xcd + (sidx >> 6) * 8;              // 0..143
  const int v = sidx & 63;
  const int bx = (st % 12) * 8 + (v & 7);            // 0..95
  const int by = (st / 12) * 8 + (v >> 3);           // 0..95

  // staging source pointers (pre-swizzled: LDS[row][chl] <- logical chl^(row&7))
  const __bf16* gA[4];
  const __bf16* gB[4];
#pragma unroll
  for (int q = 0; q < 4; ++q) {
    const int idx = q * 256 + tid;
    const int row = idx >> 3, chl = idx & 7;
    const int src = (chl ^ (row & 7)) * 8;
    gA[q] = at + (size_t)(bx * 128 + row) * 512 + src;
    gB[q] = bt + (size_t)(by * 128 + row) * 512 + src;
  }

  f32x4 acc[4][4];
#pragma unroll
  for (int i = 0; i < 4; ++i)
#pragma unroll
    for (int j = 0; j < 4; ++j) acc[i][j] = (f32x4){0.f, 0.f, 0.f, 0.f};

  auto STAGE = [&](int h, int s) {
    char* da = smem + s * 32768 + tid * 16;
    char* db = da + 16384;
    const int go = h * 64;
#pragma unroll
    for (int q = 0; q < 4; ++q) {
      async16(gA[q] + go, da + q * 4096);
      async16(gB[q] + go, db + q * 4096);
    }
  };

  STAGE(0, 0);
  asm volatile("s_waitcnt vmcnt(0)" ::: "memory");
  __builtin_amdgcn_s_barrier();

#pragma unroll
  for (int h = 0; h < 8; ++h) {
    const char* A = smem + (h & 1) * 32768;
    const char* B = A + 16384;
    if (h < 7) STAGE(h + 1, (h + 1) & 1);

#pragma unroll
    for (int kk = 0; kk < 2; ++kk) {
      bf16x8 af[4], bfr[4];
      const int phys = ((kk * 4 + lk) ^ (lr & 7)) * 16;
#pragma unroll
      for (int fj = 0; fj < 4; ++fj)
        bfr[fj] = *(const bf16x8*)(B + (wc * 64 + fj * 16 + lr) * 128 + phys);
#pragma unroll
      for (int fi = 0; fi < 4; ++fi)
        af[fi] = *(const bf16x8*)(A + (wr * 64 + fi * 16 + lr) * 128 + phys);
#pragma unroll
      for (int fi = 0; fi < 4; ++fi)
#pragma unroll
        for (int fj = 0; fj < 4; ++fj)
          acc[fi][fj] = __builtin_amdgcn_mfma_f32_16x16x32_bf16(af[fi], bfr[fj], acc[fi][fj], 0, 0, 0);
    }

    if (h < 7) {
      asm volatile("s_waitcnt vmcnt(0)" ::: "memory");  // next slot fully landed
      __builtin_amdgcn_s_barrier();                      // publish to all waves
    }
  }

  // all waves past their last reads before op-writes clobber the buffers
  asm volatile("" ::: "memory");
  __builtin_amdgcn_s_barrier();
  asm volatile("" ::: "memory");

  // ---- op tile -> LDS bf16 as A2[pair=i_l*4+j_l][k'=e*32+d], swizzled ----
#pragma unroll
  for (int fi = 0; fi < 4; ++fi) {
    const int i_l = wr * 2 + (fi >> 1);                 // lane-uniform
#pragma unroll
    for (int fj = 0; fj < 4; ++fj) {
      const int col = wc * 64 + fj * 16 + lr;
      const int j_l = col >> 5, e = col & 31;
      const int pair = i_l * 4 + j_l;
      const int cw = e * 4 + (fi & 1) * 2 + (lk >> 1);
      const int phys = cw ^ (e & 7);
      bf16x4 pk;
      pk[0] = (__bf16)acc[fi][fj][0];
      pk[1] = (__bf16)acc[fi][fj][1];
      pk[2] = (__bf16)acc[fi][fj][2];
      pk[3] = (__bf16)acc[fi][fj][3];
      *(bf16x4*)(smem + pair * 2064 + phys * 16 + (lk & 1) * 8) = pk;
    }
  }

  // GEMM2 geometry + first B-frag prefetch (hides L2 latency under barrier)
  const __bf16* wb0 = wt + (size_t)(w * 32 + lr) * 1024 + lk * 8;       // nf=0
  const __bf16* wb1 = wt + (size_t)(w * 32 + 16 + lr) * 1024 + lk * 8;  // nf=1
  bf16x8 b2a = *(const bf16x8*)(wb0);
  bf16x8 b2b = *(const bf16x8*)(wb1);

  asm volatile("s_waitcnt lgkmcnt(0)" ::: "memory");
  __builtin_amdgcn_s_barrier();

  // ---- GEMM2: C2[16 pairs][128 p], K=1024; wave w owns p-range w*32..+32 ----
  f32x4 acc2[2];
  acc2[0] = (f32x4){0.f, 0.f, 0.f, 0.f};
  acc2[1] = (f32x4){0.f, 0.f, 0.f, 0.f};

#pragma unroll 4
  for (int kk = 0; kk < 32; ++kk) {
    bf16x8 b2an, b2bn;
    if (kk < 31) {
      b2an = *(const bf16x8*)(wb0 + (kk + 1) * 32);
      b2bn = *(const bf16x8*)(wb1 + (kk + 1) * 32);
    }
    const int phys = (kk * 4 + lk) ^ (kk & 7);
    const bf16x8 a2 = *(const bf16x8*)(smem + lr * 2064 + phys * 16);
    acc2[0] = __builtin_amdgcn_mfma_f32_16x16x32_bf16(a2, b2a, acc2[0], 0, 0, 0);
    acc2[1] = __builtin_amdgcn_mfma_f32_16x16x32_bf16(a2, b2b, acc2[1], 0, 0, 0);
    b2a = b2an;
    b2b = b2bn;
  }

#pragma unroll
  for (int nf = 0; nf < 2; ++nf) {
    const int p = w * 32 + nf * 16 + lr;
    const float bo = b_out[p];
#pragma unroll
    for (int r = 0; r < 4; ++r) {
      const int pair = lk * 4 + r;
      const int i = bx * 4 + (pair >> 2);
      const int j = by * 4 + (pair & 3);
      const float pm = mkf[i] * mkf[j];
      out[((size_t)i * DN + j) * DP + p] = acc2[nf][r] * pm + bo;
    }
  }
}

extern "C" void kernel_launch(void* const* d_in, const int* in_sizes, int n_in,
                              void* d_out, int out_size, void* d_ws, size_t ws_size,
                              hipStream_t stream) {
  const float* msa      = (const float*)d_in[0];
  const void*  mask     = d_in[1];
  const void*  msa_mask = d_in[2];
  const float* gamma    = (const float*)d_in[3];
  const float* beta     = (const float*)d_in[4];
  const float* w_hidden = (const float*)d_in[5];
  const float* w_out    = (const float*)d_in[6];
  const float* b_out    = (const float*)d_in[7];
  float* out = (float*)d_out;

  char* ws = (char*)d_ws;
  __bf16* at  = (__bf16*)ws;
  __bf16* bt  = (__bf16*)(ws + OFF_BT);
  __bf16* wt  = (__bf16*)(ws + OFF_WT);
  float*  inv = (float*)(ws + OFF_INV);
  float*  smf = (float*)(ws + OFF_SMF);
  float*  mkf = (float*)(ws + OFF_MKF);

  prep_kernel<<<1026, 128, 0, stream>>>(mask, msa_mask, w_out, wt, inv, smf, mkf);
  ln_proj_kernel<<<768, 256, 0, stream>>>(msa, gamma, beta, w_hidden, inv, smf, at, bt);
  fused_kernel<<<9216, 256, 0, stream>>>(at, bt, wt, mkf, b_out, out);
}

// Round 10
// 219.718 us; speedup vs baseline: 1.8865x; 1.8865x over previous
//
#include <hip/hip_runtime.h>

#define DN 384
#define DS 512
#define DMSA 64
#define DH 32
#define DP 128

typedef __bf16 bf16x8 __attribute__((ext_vector_type(8)));
typedef __bf16 bf16x4 __attribute__((ext_vector_type(4)));
typedef float f32x4 __attribute__((ext_vector_type(4)));

// ws layout (bytes)
#define OFF_BT  12582912u
#define OFF_WT  25165824u   // wt bf16 [kk 64][p 128][ks 16] = 256KB
#define OFF_INV 25427968u
#define OFF_SMF 25428224u
#define OFF_MKF 25430272u

__device__ __forceinline__ void async16(const void* g, void* l) {
  __builtin_amdgcn_global_load_lds((const __attribute__((address_space(1))) unsigned*)g,
                                   (__attribute__((address_space(3))) unsigned*)l, 16, 0, 0);
}

// ---------------------------------------------------------------------------
// prep: masks, 1/num_msa, w_out -> wt [kk][p][ks] (k'=e*32+d).
// blocks 2..129: one per p; thread = one 16B run of wt (coalesced writes).
// ---------------------------------------------------------------------------
__global__ __launch_bounds__(128) void prep_kernel(const void* __restrict__ mask_raw,
                                                   const void* __restrict__ msa_mask_raw,
                                                   const float* __restrict__ w_out,
                                                   __bf16* __restrict__ wt,
                                                   float* __restrict__ invp,
                                                   float* __restrict__ smf,
                                                   float* __restrict__ mkf) {
  const int blk = blockIdx.x;
  const int tid = threadIdx.x;
  if (blk == 0) {
    __shared__ int sh[128];
    const unsigned int* u = (const unsigned int*)msa_mask_raw;
    int bad = (u[tid] > 1u) ? 1 : 0;
    sh[tid] = bad;
    __syncthreads();
    for (int off = 64; off > 0; off >>= 1) {
      if (tid < off) sh[tid] |= sh[tid + off];
      __syncthreads();
    }
    const int int_mode = (sh[0] == 0);
    __syncthreads();
    int cnt = 0;
    for (int q = tid; q < DS; q += 128) {
      float v;
      if (int_mode) v = (((const int*)msa_mask_raw)[q] != 0) ? 1.f : 0.f;
      else          v = (((const unsigned char*)msa_mask_raw)[q] != 0) ? 1.f : 0.f;
      smf[q] = v;
      cnt += (v != 0.f) ? 1 : 0;
    }
    sh[tid] = cnt;
    __syncthreads();
    for (int off = 64; off > 0; off >>= 1) {
      if (tid < off) sh[tid] += sh[tid + off];
      __syncthreads();
    }
    if (tid == 0) {
      float num = (float)sh[0];
      if (num < 1e-5f) num = 1e-5f;
      invp[0] = 1.0f / num;
    }
  } else if (blk == 1) {
    __shared__ int sh[128];
    const unsigned int* u = (const unsigned int*)mask_raw;
    int bad = 0;
    if (tid < 96) bad = (u[tid] > 1u) ? 1 : 0;
    sh[tid] = bad;
    __syncthreads();
    for (int off = 64; off > 0; off >>= 1) {
      if (tid < off) sh[tid] |= sh[tid + off];
      __syncthreads();
    }
    const int int_mode = (sh[0] == 0);
    __syncthreads();
    for (int q = tid; q < DN; q += 128) {
      float v;
      if (int_mode) v = (((const int*)mask_raw)[q] != 0) ? 1.f : 0.f;
      else          v = (((const unsigned char*)mask_raw)[q] != 0) ? 1.f : 0.f;
      mkf[q] = v;
    }
  } else {
    const int p = blk - 2;                        // 0..127
    const int kk = tid >> 1, ks0 = (tid & 1) * 8; // 16B run
    bf16x8 pk;
#pragma unroll
    for (int j = 0; j < 8; ++j) {
      const int kp = kk * 16 + ks0 + j;           // k' = e*32+d
      const int d = kp & 31, e = kp >> 5;
      pk[j] = (__bf16)w_out[(size_t)(d * 32 + e) * DP + p];
    }
    *(bf16x8*)(wt + ((size_t)kk * 128 + p) * 16 + ks0) = pk;
  }
}

// ---------------------------------------------------------------------------
// ln_proj v2: block = 256 rows (one n, half the s range). LN in registers ->
// bf16 x-tile to padded LDS (stride 144B) -> MFMA vs LDS-resident w_hidden^T
// -> epilogue folds msa_mask & 1/num_msa, packed 8B stores to at/bt.
// ---------------------------------------------------------------------------
__global__ __launch_bounds__(256) void ln_proj_kernel(const float* __restrict__ msa,
                                                      const float* __restrict__ gamma,
                                                      const float* __restrict__ beta,
                                                      const float* __restrict__ w_hidden,
                                                      const float* __restrict__ invp,
                                                      const float* __restrict__ smf,
                                                      __bf16* __restrict__ at,
                                                      __bf16* __restrict__ bt) {
  __shared__ __align__(16) char lds[46080];
  char* xlb = lds;            // 256 rows x 144B (64 bf16 + 16B pad)
  char* whb = lds + 36864;    // 64 rows x 144B: wh[c][d] bf16

  const int tid = threadIdx.x;
  const int b = blockIdx.x;
  const int n = b >> 1;
  const int s0 = (b & 1) << 8;

  // stage w_hidden^T: wh[c][d] = w_hidden[d][c]
  for (int idx = tid; idx < 4096; idx += 256) {
    const int d = idx >> 6, c = idx & 63;
    *(__bf16*)(whb + c * 144 + d * 2) = (__bf16)w_hidden[idx];
  }

  // ---- LN for row s = s0 + tid ----
  const int s = s0 + tid;
  const float* mp = msa + ((size_t)s * DN + n) * DMSA;
  float x[64];
  float sum = 0.f, sq = 0.f;
#pragma unroll
  for (int q = 0; q < 16; ++q) {
    float4 v = ((const float4*)mp)[q];
    x[4 * q + 0] = v.x; x[4 * q + 1] = v.y; x[4 * q + 2] = v.z; x[4 * q + 3] = v.w;
    sum += v.x + v.y + v.z + v.w;
    sq  += v.x * v.x + v.y * v.y + v.z * v.z + v.w * v.w;
  }
  const float mu = sum * (1.f / 64.f);
  const float var = sq * (1.f / 64.f) - mu * mu;
  const float rstd = rsqrtf(var + 1e-5f);
#pragma unroll
  for (int c8 = 0; c8 < 8; ++c8) {
    bf16x8 pk;
#pragma unroll
    for (int j = 0; j < 8; ++j) {
      const int d = c8 * 8 + j;
      pk[j] = (__bf16)((x[d] - mu) * rstd * gamma[d] + beta[d]);
    }
    *(bf16x8*)(xlb + tid * 144 + c8 * 16) = pk;
  }
  __syncthreads();

  // ---- MFMA: wave w owns rows w*64..+64; C[row=s][col=c], K=64 ----
  const int l = tid & 63, w = tid >> 6;
  const int lr = l & 15, lk = l >> 4;

  bf16x8 bfr[4][2];
#pragma unroll
  for (int fj = 0; fj < 4; ++fj)
#pragma unroll
    for (int kk = 0; kk < 2; ++kk)
      bfr[fj][kk] = *(const bf16x8*)(whb + (fj * 16 + lr) * 144 + (kk * 4 + lk) * 16);

  f32x4 acc[4][4];
#pragma unroll
  for (int i = 0; i < 4; ++i)
#pragma unroll
    for (int j = 0; j < 4; ++j) acc[i][j] = (f32x4){0.f, 0.f, 0.f, 0.f};

#pragma unroll
  for (int fi = 0; fi < 4; ++fi) {
    bf16x8 af[2];
#pragma unroll
    for (int kk = 0; kk < 2; ++kk)
      af[kk] = *(const bf16x8*)(xlb + (w * 64 + fi * 16 + lr) * 144 + (kk * 4 + lk) * 16);
#pragma unroll
    for (int fj = 0; fj < 4; ++fj)
#pragma unroll
      for (int kk = 0; kk < 2; ++kk)
        acc[fi][fj] = __builtin_amdgcn_mfma_f32_16x16x32_bf16(af[kk], bfr[fj][kk], acc[fi][fj], 0, 0, 0);
  }

  // ---- epilogue: fold masks, write packed 4-s runs ----
  const float inv = invp[0];
#pragma unroll
  for (int fi = 0; fi < 4; ++fi) {
    const int sg = s0 + w * 64 + fi * 16 + lk * 4;
    const float4 smv = *(const float4*)(smf + sg);
    float smr[4] = {smv.x, smv.y, smv.z, smv.w};
#pragma unroll
    for (int fj = 0; fj < 4; ++fj) {
      const int c = fj * 16 + lr;
      bf16x4 pk;
      if (fj < 2) {
#pragma unroll
        for (int r = 0; r < 4; ++r) pk[r] = (__bf16)(acc[fi][fj][r] * smr[r] * inv);
        *(bf16x4*)(at + ((size_t)n * DH + c) * DS + sg) = pk;
      } else {
#pragma unroll
        for (int r = 0; r < 4; ++r) pk[r] = (__bf16)(acc[fi][fj][r] * smr[r]);
        *(bf16x4*)(bt + ((size_t)n * DH + (c - 32)) * DS + sg) = pk;
      }
    }
  }
}

// ---------------------------------------------------------------------------
// fused (round-7 best): GEMM1 256x256xK512, BK=64 dbuf (2x64KB), 8 K-steps,
// coarse loop {stage-early, conflict-free swizzled reads, 64 MFMA,
// vmcnt(0)+barrier}. Then op->LDS (swizzled) -> GEMM2 via 32x32x16
// (wt [kk][p][16], rolling prefetch) -> pair_mask + b_out epilogue.
// ---------------------------------------------------------------------------
__global__ __launch_bounds__(512, 2) void fused_kernel(const __bf16* __restrict__ at,
                                                       const __bf16* __restrict__ bt,
                                                       const __bf16* __restrict__ wt,
                                                       const float* __restrict__ mkf,
                                                       const float* __restrict__ b_out,
                                                       float* __restrict__ out) {
  __shared__ __align__(128) char smem[132096];

  const int tid = threadIdx.x;
  const int l = tid & 63, w = tid >> 6;
  const int lr = l & 15, lk = l >> 4;
  const int wr = w >> 2, wc = w & 3;

  // XCD-aware swizzle: 48 supertiles of 8x6 blocks.
  const int orig = blockIdx.x;
  const int xcd = orig & 7, sidx = orig >> 3;
  const int stl = sidx / 48, u = sidx % 48;
  const int stg = xcd + stl * 8;
  const int stx = stg % 6, sty = stg / 6;
  const int bx = stx * 8 + (u & 7);
  const int by = sty * 6 + (u >> 3);

  // staging source pointers (pre-swizzled: LDS[row][chl] <- logical chl^(row&7))
  const __bf16* gA[4];
  const __bf16* gB[4];
#pragma unroll
  for (int q = 0; q < 4; ++q) {
    const int idx = q * 512 + tid;
    const int row = idx >> 3, chl = idx & 7;
    const int src = (chl ^ (row & 7)) * 8;
    gA[q] = at + (size_t)(bx * 256 + row) * 512 + src;
    gB[q] = bt + (size_t)(by * 256 + row) * 512 + src;
  }

  f32x4 acc[8][4];
#pragma unroll
  for (int i = 0; i < 8; ++i)
#pragma unroll
    for (int j = 0; j < 4; ++j) acc[i][j] = (f32x4){0.f, 0.f, 0.f, 0.f};

  auto STAGE = [&](int h, int s) {
    char* da = smem + s * 65536 + tid * 16;
    char* db = da + 32768;
    const int go = h * 64;
#pragma unroll
    for (int q = 0; q < 4; ++q) {
      async16(gA[q] + go, da + q * 8192);
      async16(gB[q] + go, db + q * 8192);
    }
  };

  STAGE(0, 0);
  asm volatile("s_waitcnt vmcnt(0)" ::: "memory");
  __builtin_amdgcn_s_barrier();

#pragma unroll
  for (int h = 0; h < 8; ++h) {
    const char* A = smem + (h & 1) * 65536;
    const char* B = A + 32768;
    if (h < 7) STAGE(h + 1, (h + 1) & 1);

#pragma unroll
    for (int kk = 0; kk < 2; ++kk) {
      bf16x8 af[8], bfr[4];
      const int c = kk * 4 + lk;
      const int phys = (c ^ (lr & 7)) * 16;
#pragma unroll
      for (int fj = 0; fj < 4; ++fj) {
        const int r = wc * 64 + fj * 16 + lr;
        bfr[fj] = *(const bf16x8*)(B + r * 128 + phys);
      }
#pragma unroll
      for (int fi = 0; fi < 8; ++fi) {
        const int r = wr * 128 + fi * 16 + lr;
        af[fi] = *(const bf16x8*)(A + r * 128 + phys);
      }
#pragma unroll
      for (int fi = 0; fi < 8; ++fi)
#pragma unroll
        for (int fj = 0; fj < 4; ++fj)
          acc[fi][fj] = __builtin_amdgcn_mfma_f32_16x16x32_bf16(af[fi], bfr[fj], acc[fi][fj], 0, 0, 0);
    }

    if (h < 7) {
      asm volatile("s_waitcnt vmcnt(0)" ::: "memory");
      __builtin_amdgcn_s_barrier();
    }
  }

  asm volatile("" ::: "memory");
  __builtin_amdgcn_s_barrier();
  asm volatile("" ::: "memory");

  // ---- op tile -> LDS bf16 as A2[pair][k'=e*32+d], chunk-XOR swizzled ----
#pragma unroll
  for (int fi = 0; fi < 8; ++fi) {
    const int i_l = wr * 4 + (fi >> 1);
#pragma unroll
    for (int fj = 0; fj < 4; ++fj) {
      const int col = wc * 64 + fj * 16 + lr;
      const int j_l = col >> 5, e = col & 31;
      const int pair = i_l * 8 + j_l;
      const int cw = e * 4 + (fi & 1) * 2 + (lk >> 1);
      const int phys = cw ^ (e & 7);
      bf16x4 pk;
      pk[0] = (__bf16)acc[fi][fj][0];
      pk[1] = (__bf16)acc[fi][fj][1];
      pk[2] = (__bf16)acc[fi][fj][2];
      pk[3] = (__bf16)acc[fi][fj][3];
      *(bf16x4*)(smem + pair * 2064 + phys * 16 + (lk & 1) * 8) = pk;
    }
  }

  // GEMM2 geometry + first B-frag prefetch
  const int mf = w >> 2, pf = w & 3;
  const int l31 = l & 31, lh = l >> 5;
  const __bf16* wb = wt + (size_t)(pf * 32 + l31) * 16 + lh * 8;  // + kk*2048
  bf16x8 b2 = *(const bf16x8*)(wb);

  asm volatile("s_waitcnt lgkmcnt(0)" ::: "memory");
  __builtin_amdgcn_s_barrier();

  // ---- GEMM2: C2[64 pairs][128 p], K=1024, 32x32x16 MFMA, 1 frag/wave ----
  float acc2[16];
#pragma unroll
  for (int q = 0; q < 16; ++q) acc2[q] = 0.f;
  typedef float f32x16 __attribute__((ext_vector_type(16)));
  f32x16& acc2v = *(f32x16*)acc2;

  const char* aBase = smem + (mf * 32 + l31) * 2064;
#pragma unroll 4
  for (int kk = 0; kk < 64; ++kk) {
    bf16x8 b2n;
    if (kk < 63) b2n = *(const bf16x8*)(wb + (size_t)(kk + 1) * 2048);
    const int cw = kk * 2 + lh;
    const int phys = cw ^ ((kk >> 1) & 7);
    const bf16x8 a2 = *(const bf16x8*)(aBase + phys * 16);
    acc2v = __builtin_amdgcn_mfma_f32_32x32x16_bf16(a2, b2, acc2v, 0, 0, 0);
    b2 = b2n;
  }

  const int p = pf * 32 + l31;
  const float bo = b_out[p];
#pragma unroll
  for (int reg = 0; reg < 16; ++reg) {
    const int pair = mf * 32 + (reg & 3) + 8 * (reg >> 2) + 4 * lh;
    const int i = bx * 8 + (pair >> 3);
    const int j = by * 8 + (pair & 7);
    const float pm = mkf[i] * mkf[j];
    out[((size_t)i * DN + j) * DP + p] = acc2[reg] * pm + bo;
  }
}

extern "C" void kernel_launch(void* const* d_in, const int* in_sizes, int n_in,
                              void* d_out, int out_size, void* d_ws, size_t ws_size,
                              hipStream_t stream) {
  const float* msa      = (const float*)d_in[0];
  const void*  mask     = d_in[1];
  const void*  msa_mask = d_in[2];
  const float* gamma    = (const float*)d_in[3];
  const float* beta     = (const float*)d_in[4];
  const float* w_hidden = (const float*)d_in[5];
  const float* w_out    = (const float*)d_in[6];
  const float* b_out    = (const float*)d_in[7];
  float* out = (float*)d_out;

  char* ws = (char*)d_ws;
  __bf16* at  = (__bf16*)ws;
  __bf16* bt  = (__bf16*)(ws + OFF_BT);
  __bf16* wt  = (__bf16*)(ws + OFF_WT);
  float*  inv = (float*)(ws + OFF_INV);
  float*  smf = (float*)(ws + OFF_SMF);
  float*  mkf = (float*)(ws + OFF_MKF);

  prep_kernel<<<130, 128, 0, stream>>>(mask, msa_mask, w_out, wt, inv, smf, mkf);
  ln_proj_kernel<<<768, 256, 0, stream>>>(msa, gamma, beta, w_hidden, inv, smf, at, bt);
  fused_kernel<<<2304, 512, 0, stream>>>(at, bt, wt, mkf, b_out, out);
}

// Round 11
// 194.149 us; speedup vs baseline: 2.1350x; 1.1317x over previous
//
#include <hip/hip_runtime.h>

#define DN 384
#define DS 512
#define DMSA 64
#define DH 32
#define DP 128

typedef __bf16 bf16x8 __attribute__((ext_vector_type(8)));
typedef __bf16 bf16x4 __attribute__((ext_vector_type(4)));
typedef float f32x4 __attribute__((ext_vector_type(4)));
typedef float f32x16 __attribute__((ext_vector_type(16)));

// ws layout (bytes)
#define OFF_BT  12582912u
#define OFF_WT  25165824u   // wt bf16 [kk 64][p 128][ks 16] = 256KB
#define OFF_INV 25427968u
#define OFF_SMF 25428224u
#define OFF_MKF 25430272u

__device__ __forceinline__ void async16(const void* g, void* l) {
  __builtin_amdgcn_global_load_lds((const __attribute__((address_space(1))) unsigned*)g,
                                   (__attribute__((address_space(3))) unsigned*)l, 16, 0, 0);
}

// ---------------------------------------------------------------------------
// prep: masks, 1/num_msa, w_out -> wt [kk][p][ks] (k'=e*32+d).
// blocks 2..129: one per p; thread = one 16B run of wt (coalesced writes).
// ---------------------------------------------------------------------------
__global__ __launch_bounds__(128) void prep_kernel(const void* __restrict__ mask_raw,
                                                   const void* __restrict__ msa_mask_raw,
                                                   const float* __restrict__ w_out,
                                                   __bf16* __restrict__ wt,
                                                   float* __restrict__ invp,
                                                   float* __restrict__ smf,
                                                   float* __restrict__ mkf) {
  const int blk = blockIdx.x;
  const int tid = threadIdx.x;
  if (blk == 0) {
    __shared__ int sh[128];
    const unsigned int* u = (const unsigned int*)msa_mask_raw;
    int bad = (u[tid] > 1u) ? 1 : 0;
    sh[tid] = bad;
    __syncthreads();
    for (int off = 64; off > 0; off >>= 1) {
      if (tid < off) sh[tid] |= sh[tid + off];
      __syncthreads();
    }
    const int int_mode = (sh[0] == 0);
    __syncthreads();
    int cnt = 0;
    for (int q = tid; q < DS; q += 128) {
      float v;
      if (int_mode) v = (((const int*)msa_mask_raw)[q] != 0) ? 1.f : 0.f;
      else          v = (((const unsigned char*)msa_mask_raw)[q] != 0) ? 1.f : 0.f;
      smf[q] = v;
      cnt += (v != 0.f) ? 1 : 0;
    }
    sh[tid] = cnt;
    __syncthreads();
    for (int off = 64; off > 0; off >>= 1) {
      if (tid < off) sh[tid] += sh[tid + off];
      __syncthreads();
    }
    if (tid == 0) {
      float num = (float)sh[0];
      if (num < 1e-5f) num = 1e-5f;
      invp[0] = 1.0f / num;
    }
  } else if (blk == 1) {
    __shared__ int sh[128];
    const unsigned int* u = (const unsigned int*)mask_raw;
    int bad = 0;
    if (tid < 96) bad = (u[tid] > 1u) ? 1 : 0;
    sh[tid] = bad;
    __syncthreads();
    for (int off = 64; off > 0; off >>= 1) {
      if (tid < off) sh[tid] |= sh[tid + off];
      __syncthreads();
    }
    const int int_mode = (sh[0] == 0);
    __syncthreads();
    for (int q = tid; q < DN; q += 128) {
      float v;
      if (int_mode) v = (((const int*)mask_raw)[q] != 0) ? 1.f : 0.f;
      else          v = (((const unsigned char*)mask_raw)[q] != 0) ? 1.f : 0.f;
      mkf[q] = v;
    }
  } else {
    const int p = blk - 2;                        // 0..127
    const int kk = tid >> 1, ks0 = (tid & 1) * 8; // 16B run
    bf16x8 pk;
#pragma unroll
    for (int j = 0; j < 8; ++j) {
      const int kp = kk * 16 + ks0 + j;           // k' = e*32+d
      const int d = kp & 31, e = kp >> 5;
      pk[j] = (__bf16)w_out[(size_t)(d * 32 + e) * DP + p];
    }
    *(bf16x8*)(wt + ((size_t)kk * 128 + p) * 16 + ks0) = pk;
  }
}

// ---------------------------------------------------------------------------
// ln_proj v2: block = 256 rows (one n, half the s range). LN in registers ->
// bf16 x-tile to padded LDS (stride 144B) -> MFMA vs LDS-resident w_hidden^T
// -> epilogue folds msa_mask & 1/num_msa, packed 8B stores to at/bt.
// ---------------------------------------------------------------------------
__global__ __launch_bounds__(256) void ln_proj_kernel(const float* __restrict__ msa,
                                                      const float* __restrict__ gamma,
                                                      const float* __restrict__ beta,
                                                      const float* __restrict__ w_hidden,
                                                      const float* __restrict__ invp,
                                                      const float* __restrict__ smf,
                                                      __bf16* __restrict__ at,
                                                      __bf16* __restrict__ bt) {
  __shared__ __align__(16) char lds[46080];
  char* xlb = lds;            // 256 rows x 144B (64 bf16 + 16B pad)
  char* whb = lds + 36864;    // 64 rows x 144B: wh[c][d] bf16

  const int tid = threadIdx.x;
  const int b = blockIdx.x;
  const int n = b >> 1;
  const int s0 = (b & 1) << 8;

  // stage w_hidden^T: wh[c][d] = w_hidden[d][c]
  for (int idx = tid; idx < 4096; idx += 256) {
    const int d = idx >> 6, c = idx & 63;
    *(__bf16*)(whb + c * 144 + d * 2) = (__bf16)w_hidden[idx];
  }

  // ---- LN for row s = s0 + tid ----
  const int s = s0 + tid;
  const float* mp = msa + ((size_t)s * DN + n) * DMSA;
  float x[64];
  float sum = 0.f, sq = 0.f;
#pragma unroll
  for (int q = 0; q < 16; ++q) {
    float4 v = ((const float4*)mp)[q];
    x[4 * q + 0] = v.x; x[4 * q + 1] = v.y; x[4 * q + 2] = v.z; x[4 * q + 3] = v.w;
    sum += v.x + v.y + v.z + v.w;
    sq  += v.x * v.x + v.y * v.y + v.z * v.z + v.w * v.w;
  }
  const float mu = sum * (1.f / 64.f);
  const float var = sq * (1.f / 64.f) - mu * mu;
  const float rstd = rsqrtf(var + 1e-5f);
#pragma unroll
  for (int c8 = 0; c8 < 8; ++c8) {
    bf16x8 pk;
#pragma unroll
    for (int j = 0; j < 8; ++j) {
      const int d = c8 * 8 + j;
      pk[j] = (__bf16)((x[d] - mu) * rstd * gamma[d] + beta[d]);
    }
    *(bf16x8*)(xlb + tid * 144 + c8 * 16) = pk;
  }
  __syncthreads();

  // ---- MFMA: wave w owns rows w*64..+64; C[row=s][col=c], K=64 ----
  const int l = tid & 63, w = tid >> 6;
  const int lr = l & 15, lk = l >> 4;

  bf16x8 bfr[4][2];
#pragma unroll
  for (int fj = 0; fj < 4; ++fj)
#pragma unroll
    for (int kk = 0; kk < 2; ++kk)
      bfr[fj][kk] = *(const bf16x8*)(whb + (fj * 16 + lr) * 144 + (kk * 4 + lk) * 16);

  f32x4 acc[4][4];
#pragma unroll
  for (int i = 0; i < 4; ++i)
#pragma unroll
    for (int j = 0; j < 4; ++j) acc[i][j] = (f32x4){0.f, 0.f, 0.f, 0.f};

#pragma unroll
  for (int fi = 0; fi < 4; ++fi) {
    bf16x8 af[2];
#pragma unroll
    for (int kk = 0; kk < 2; ++kk)
      af[kk] = *(const bf16x8*)(xlb + (w * 64 + fi * 16 + lr) * 144 + (kk * 4 + lk) * 16);
#pragma unroll
    for (int fj = 0; fj < 4; ++fj)
#pragma unroll
      for (int kk = 0; kk < 2; ++kk)
        acc[fi][fj] = __builtin_amdgcn_mfma_f32_16x16x32_bf16(af[kk], bfr[fj][kk], acc[fi][fj], 0, 0, 0);
  }

  // ---- epilogue: fold masks, write packed 4-s runs ----
  const float inv = invp[0];
#pragma unroll
  for (int fi = 0; fi < 4; ++fi) {
    const int sg = s0 + w * 64 + fi * 16 + lk * 4;
    const float4 smv = *(const float4*)(smf + sg);
    float smr[4] = {smv.x, smv.y, smv.z, smv.w};
#pragma unroll
    for (int fj = 0; fj < 4; ++fj) {
      const int c = fj * 16 + lr;
      bf16x4 pk;
      if (fj < 2) {
#pragma unroll
        for (int r = 0; r < 4; ++r) pk[r] = (__bf16)(acc[fi][fj][r] * smr[r] * inv);
        *(bf16x4*)(at + ((size_t)n * DH + c) * DS + sg) = pk;
      } else {
#pragma unroll
        for (int r = 0; r < 4; ++r) pk[r] = (__bf16)(acc[fi][fj][r] * smr[r]);
        *(bf16x4*)(bt + ((size_t)n * DH + (c - 32)) * DS + sg) = pk;
      }
    }
  }
}

// ---------------------------------------------------------------------------
// fused: GEMM1 256x256xK512 (round-7 coarse loop, conflict-free swizzle) ->
// op->LDS (swizzled) -> GEMM2 via 32x32x16 with 2-window (8+8) software-
// pipelined wt loads (window w+1 issued before window w's MFMAs; window 0
// issued before the opl-drain barrier) -> pair_mask + b_out epilogue.
// ---------------------------------------------------------------------------
__global__ __launch_bounds__(512, 2) void fused_kernel(const __bf16* __restrict__ at,
                                                       const __bf16* __restrict__ bt,
                                                       const __bf16* __restrict__ wt,
                                                       const float* __restrict__ mkf,
                                                       const float* __restrict__ b_out,
                                                       float* __restrict__ out) {
  __shared__ __align__(128) char smem[132096];

  const int tid = threadIdx.x;
  const int l = tid & 63, w = tid >> 6;
  const int lr = l & 15, lk = l >> 4;
  const int wr = w >> 2, wc = w & 3;

  // XCD-aware swizzle: 48 supertiles of 8x6 blocks.
  const int orig = blockIdx.x;
  const int xcd = orig & 7, sidx = orig >> 3;
  const int stl = sidx / 48, u = sidx % 48;
  const int stg = xcd + stl * 8;
  const int stx = stg % 6, sty = stg / 6;
  const int bx = stx * 8 + (u & 7);
  const int by = sty * 6 + (u >> 3);

  // staging source pointers (pre-swizzled: LDS[row][chl] <- logical chl^(row&7))
  const __bf16* gA[4];
  const __bf16* gB[4];
#pragma unroll
  for (int q = 0; q < 4; ++q) {
    const int idx = q * 512 + tid;
    const int row = idx >> 3, chl = idx & 7;
    const int src = (chl ^ (row & 7)) * 8;
    gA[q] = at + (size_t)(bx * 256 + row) * 512 + src;
    gB[q] = bt + (size_t)(by * 256 + row) * 512 + src;
  }

  f32x4 acc[8][4];
#pragma unroll
  for (int i = 0; i < 8; ++i)
#pragma unroll
    for (int j = 0; j < 4; ++j) acc[i][j] = (f32x4){0.f, 0.f, 0.f, 0.f};

  auto STAGE = [&](int h, int s) {
    char* da = smem + s * 65536 + tid * 16;
    char* db = da + 32768;
    const int go = h * 64;
#pragma unroll
    for (int q = 0; q < 4; ++q) {
      async16(gA[q] + go, da + q * 8192);
      async16(gB[q] + go, db + q * 8192);
    }
  };

  STAGE(0, 0);
  asm volatile("s_waitcnt vmcnt(0)" ::: "memory");
  __builtin_amdgcn_s_barrier();

#pragma unroll
  for (int h = 0; h < 8; ++h) {
    const char* A = smem + (h & 1) * 65536;
    const char* B = A + 32768;
    if (h < 7) STAGE(h + 1, (h + 1) & 1);

#pragma unroll
    for (int kk = 0; kk < 2; ++kk) {
      bf16x8 af[8], bfr[4];
      const int c = kk * 4 + lk;
      const int phys = (c ^ (lr & 7)) * 16;
#pragma unroll
      for (int fj = 0; fj < 4; ++fj) {
        const int r = wc * 64 + fj * 16 + lr;
        bfr[fj] = *(const bf16x8*)(B + r * 128 + phys);
      }
#pragma unroll
      for (int fi = 0; fi < 8; ++fi) {
        const int r = wr * 128 + fi * 16 + lr;
        af[fi] = *(const bf16x8*)(A + r * 128 + phys);
      }
#pragma unroll
      for (int fi = 0; fi < 8; ++fi)
#pragma unroll
        for (int fj = 0; fj < 4; ++fj)
          acc[fi][fj] = __builtin_amdgcn_mfma_f32_16x16x32_bf16(af[fi], bfr[fj], acc[fi][fj], 0, 0, 0);
    }

    if (h < 7) {
      asm volatile("s_waitcnt vmcnt(0)" ::: "memory");
      __builtin_amdgcn_s_barrier();
    }
  }

  asm volatile("" ::: "memory");
  __builtin_amdgcn_s_barrier();
  asm volatile("" ::: "memory");

  // ---- op tile -> LDS bf16 as A2[pair][k'=e*32+d], chunk-XOR swizzled ----
#pragma unroll
  for (int fi = 0; fi < 8; ++fi) {
    const int i_l = wr * 4 + (fi >> 1);
#pragma unroll
    for (int fj = 0; fj < 4; ++fj) {
      const int col = wc * 64 + fj * 16 + lr;
      const int j_l = col >> 5, e = col & 31;
      const int pair = i_l * 8 + j_l;
      const int cw = e * 4 + (fi & 1) * 2 + (lk >> 1);
      const int phys = cw ^ (e & 7);
      bf16x4 pk;
      pk[0] = (__bf16)acc[fi][fj][0];
      pk[1] = (__bf16)acc[fi][fj][1];
      pk[2] = (__bf16)acc[fi][fj][2];
      pk[3] = (__bf16)acc[fi][fj][3];
      *(bf16x4*)(smem + pair * 2064 + phys * 16 + (lk & 1) * 8) = pk;
    }
  }

  // GEMM2 geometry; issue window-0 wt loads before the drain barrier (T14)
  const int mf = w >> 2, pf = w & 3;
  const int l31 = l & 31, lh = l >> 5;
  const __bf16* wb = wt + (size_t)(pf * 32 + l31) * 16 + lh * 8;  // + kk*2048

  bf16x8 bw[8], bn[8];
#pragma unroll
  for (int j = 0; j < 8; ++j)
    bw[j] = *(const bf16x8*)(wb + (size_t)j * 2048);

  asm volatile("s_waitcnt lgkmcnt(0)" ::: "memory");
  __builtin_amdgcn_s_barrier();

  // ---- GEMM2: C2[64 pairs][128 p], K=1024, 32x32x16 MFMA, 1 frag/wave ----
  // 2-window pipeline: loads for window wnd+1 issue before window wnd's MFMAs.
  f32x16 acc2v;
#pragma unroll
  for (int q = 0; q < 16; ++q) acc2v[q] = 0.f;

  const char* aBase = smem + (mf * 32 + l31) * 2064;
#pragma unroll
  for (int wnd = 0; wnd < 8; ++wnd) {
    if (wnd < 7) {
#pragma unroll
      for (int j = 0; j < 8; ++j)
        bn[j] = *(const bf16x8*)(wb + (size_t)((wnd + 1) * 8 + j) * 2048);
    }
#pragma unroll
    for (int j = 0; j < 8; ++j) {
      const int kk = wnd * 8 + j;
      const int cw = kk * 2 + lh;
      const int phys = cw ^ ((kk >> 1) & 7);
      const bf16x8 a2 = *(const bf16x8*)(aBase + phys * 16);
      acc2v = __builtin_amdgcn_mfma_f32_32x32x16_bf16(a2, bw[j], acc2v, 0, 0, 0);
    }
#pragma unroll
    for (int j = 0; j < 8; ++j) bw[j] = bn[j];
  }

  const int p = pf * 32 + l31;
  const float bo = b_out[p];
#pragma unroll
  for (int reg = 0; reg < 16; ++reg) {
    const int pair = mf * 32 + (reg & 3) + 8 * (reg >> 2) + 4 * lh;
    const int i = bx * 8 + (pair >> 3);
    const int j = by * 8 + (pair & 7);
    const float pm = mkf[i] * mkf[j];
    out[((size_t)i * DN + j) * DP + p] = acc2v[reg] * pm + bo;
  }
}

extern "C" void kernel_launch(void* const* d_in, const int* in_sizes, int n_in,
                              void* d_out, int out_size, void* d_ws, size_t ws_size,
                              hipStream_t stream) {
  const float* msa      = (const float*)d_in[0];
  const void*  mask     = d_in[1];
  const void*  msa_mask = d_in[2];
  const float* gamma    = (const float*)d_in[3];
  const float* beta     = (const float*)d_in[4];
  const float* w_hidden = (const float*)d_in[5];
  const float* w_out    = (const float*)d_in[6];
  const float* b_out    = (const float*)d_in[7];
  float* out = (float*)d_out;

  char* ws = (char*)d_ws;
  __bf16* at  = (__bf16*)ws;
  __bf16* bt  = (__bf16*)(ws + OFF_BT);
  __bf16* wt  = (__bf16*)(ws + OFF_WT);
  float*  inv = (float*)(ws + OFF_INV);
  float*  smf = (float*)(ws + OFF_SMF);
  float*  mkf = (float*)(ws + OFF_MKF);

  prep_kernel<<<130, 128, 0, stream>>>(mask, msa_mask, w_out, wt, inv, smf, mkf);
  ln_proj_kernel<<<768, 256, 0, stream>>>(msa, gamma, beta, w_hidden, inv, smf, at, bt);
  fused_kernel<<<2304, 512, 0, stream>>>(at, bt, wt, mkf, b_out, out);
}

// Round 12
// 128.233 us; speedup vs baseline: 3.2325x; 1.5140x over previous
//
#include <hip/hip_runtime.h>

#define DN 384
#define DS 512
#define DMSA 64
#define DH 32
#define DP 128

typedef __bf16 bf16x8 __attribute__((ext_vector_type(8)));
typedef __bf16 bf16x4 __attribute__((ext_vector_type(4)));
typedef float f32x4 __attribute__((ext_vector_type(4)));
typedef float f32x16 __attribute__((ext_vector_type(16)));

// ws layout (bytes)
#define OFF_BT    12582912u
#define OFF_WT    25165824u   // wt bf16 [kk 64][p 128][ks 16] = 256KB
#define OFF_INV   25427968u   // 1 f32
#define OFF_CNT   25428032u   // [scnt, ncnt]
#define OFF_SPERM 25428224u   // 512 i32
#define OFF_NPERM 25430272u   // 392 i32 (padded with 0)
#define OFF_TRASH 25432064u   // 32KB float trash for invalid-pair stores

__device__ __forceinline__ void async16(const void* g, void* l) {
  __builtin_amdgcn_global_load_lds((const __attribute__((address_space(1))) unsigned*)g,
                                   (__attribute__((address_space(3))) unsigned*)l, 16, 0, 0);
}

// ---------------------------------------------------------------------------
// prep: mask compaction (sperm/nperm/counts/inv) + w_out -> wt [kk][p][ks].
// ---------------------------------------------------------------------------
__global__ __launch_bounds__(128) void prep_kernel(const void* __restrict__ mask_raw,
                                                   const void* __restrict__ msa_mask_raw,
                                                   const float* __restrict__ w_out,
                                                   __bf16* __restrict__ wt,
                                                   float* __restrict__ invp,
                                                   int* __restrict__ cnt,
                                                   int* __restrict__ sperm,
                                                   int* __restrict__ nperm) {
  const int blk = blockIdx.x;
  const int tid = threadIdx.x;
  if (blk == 0) {
    // msa_mask: 512 elements -> sperm, scnt, inv
    __shared__ int sh[128];
    __shared__ float sv[512];
    __shared__ int sp[512];
    __shared__ int csh;
    const unsigned int* u = (const unsigned int*)msa_mask_raw;
    sh[tid] = (u[tid] > 1u) ? 1 : 0;   // first 128 ints = 512B, safe either dtype
    __syncthreads();
    for (int off = 64; off > 0; off >>= 1) {
      if (tid < off) sh[tid] |= sh[tid + off];
      __syncthreads();
    }
    const int int_mode = (sh[0] == 0);
    __syncthreads();
    for (int q = tid; q < DS; q += 128) {
      float v;
      if (int_mode) v = (((const int*)msa_mask_raw)[q] != 0) ? 1.f : 0.f;
      else          v = (((const unsigned char*)msa_mask_raw)[q] != 0) ? 1.f : 0.f;
      sv[q] = v;
    }
    __syncthreads();
    if (tid == 0) {
      int c = 0;
      for (int s = 0; s < DS; ++s)
        if (sv[s] != 0.f) sp[c++] = s;
      csh = c;
      cnt[0] = c;
      float num = (float)c;
      if (num < 1e-5f) num = 1e-5f;
      invp[0] = 1.0f / num;
    }
    __syncthreads();
    const int c = csh;
    for (int q = tid; q < c; q += 128) sperm[q] = sp[q];
  } else if (blk == 1) {
    // mask: 384 elements -> nperm (padded to 392 with 0), ncnt
    __shared__ int sh[128];
    __shared__ float sv[384];
    __shared__ int sp[384];
    __shared__ int csh;
    const unsigned int* u = (const unsigned int*)mask_raw;
    sh[tid] = (tid < 96) ? ((u[tid] > 1u) ? 1 : 0) : 0;
    __syncthreads();
    for (int off = 64; off > 0; off >>= 1) {
      if (tid < off) sh[tid] |= sh[tid + off];
      __syncthreads();
    }
    const int int_mode = (sh[0] == 0);
    __syncthreads();
    for (int q = tid; q < DN; q += 128) {
      float v;
      if (int_mode) v = (((const int*)mask_raw)[q] != 0) ? 1.f : 0.f;
      else          v = (((const unsigned char*)mask_raw)[q] != 0) ? 1.f : 0.f;
      sv[q] = v;
    }
    __syncthreads();
    if (tid == 0) {
      int c = 0;
      for (int n = 0; n < DN; ++n)
        if (sv[n] != 0.f) sp[c++] = n;
      csh = c;
      cnt[1] = c;
    }
    __syncthreads();
    const int c = csh;
    for (int q = tid; q < 392; q += 128) nperm[q] = (q < c) ? sp[q] : 0;
  } else {
    const int p = blk - 2;                        // 0..127
    const int kk = tid >> 1, ks0 = (tid & 1) * 8; // 16B run
    bf16x8 pk;
#pragma unroll
    for (int j = 0; j < 8; ++j) {
      const int kp = kk * 16 + ks0 + j;           // k' = e*32+d
      const int d = kp & 31, e = kp >> 5;
      pk[j] = (__bf16)w_out[(size_t)(d * 32 + e) * DP + p];
    }
    *(bf16x8*)(wt + ((size_t)kk * 128 + p) * 16 + ks0) = pk;
  }
}

// ---------------------------------------------------------------------------
// fill: out[i][j][:] = b_out for ALL pairs (valid pairs overwritten by fused).
// ---------------------------------------------------------------------------
__global__ __launch_bounds__(256) void fill_kernel(const float* __restrict__ b_out,
                                                   float* __restrict__ out) {
  const size_t q0 = (size_t)blockIdx.x * 2048 + threadIdx.x * 8;
  const float4* bo4 = (const float4*)b_out;
  float4* o4 = (float4*)out;
#pragma unroll
  for (int r = 0; r < 8; ++r) {
    const size_t q = q0 + r;
    o4[q] = bo4[q & 31];
  }
}

// ---------------------------------------------------------------------------
// ln_proj v3 (compacted): block (cn, hf). Active threads LN from
// msa[sperm[cs]][nperm[cn]]; pad threads contribute zeros. MFMA projection,
// epilogue writes at/bt[(cn*32+c)][cs] (a scaled by 1/num_msa).
// ---------------------------------------------------------------------------
__global__ __launch_bounds__(256) void ln_proj_kernel(const float* __restrict__ msa,
                                                      const float* __restrict__ gamma,
                                                      const float* __restrict__ beta,
                                                      const float* __restrict__ w_hidden,
                                                      const float* __restrict__ invp,
                                                      const int* __restrict__ cnt,
                                                      const int* __restrict__ sperm,
                                                      const int* __restrict__ nperm,
                                                      __bf16* __restrict__ at,
                                                      __bf16* __restrict__ bt) {
  __shared__ __align__(16) char lds[46080];
  char* xlb = lds;            // 256 rows x 144B (64 bf16 + 16B pad)
  char* whb = lds + 36864;    // 64 rows x 144B: wh[c][d] bf16

  const int tid = threadIdx.x;
  const int b = blockIdx.x;
  const int cn = b >> 1;
  const int hf = b & 1;

  const int scnt = cnt[0], ncnt = cnt[1];
  const int ntile8 = ((ncnt + 7) >> 3) << 3;
  if (cn >= ntile8) return;

  // stage w_hidden^T: wh[c][d] = w_hidden[d][c]
  for (int idx = tid; idx < 4096; idx += 256) {
    const int d = idx >> 6, c = idx & 63;
    *(__bf16*)(whb + c * 144 + d * 2) = (__bf16)w_hidden[idx];
  }

  const int cs = (hf << 8) + tid;
  const bool act = (cn < ncnt) && (cs < scnt);

  if (act) {
    const int n = nperm[cn];
    const int s = sperm[cs];
    const float* mp = msa + ((size_t)s * DN + n) * DMSA;
    float x[64];
    float sum = 0.f, sq = 0.f;
#pragma unroll
    for (int q = 0; q < 16; ++q) {
      float4 v = ((const float4*)mp)[q];
      x[4 * q + 0] = v.x; x[4 * q + 1] = v.y; x[4 * q + 2] = v.z; x[4 * q + 3] = v.w;
      sum += v.x + v.y + v.z + v.w;
      sq  += v.x * v.x + v.y * v.y + v.z * v.z + v.w * v.w;
    }
    const float mu = sum * (1.f / 64.f);
    const float var = sq * (1.f / 64.f) - mu * mu;
    const float rstd = rsqrtf(var + 1e-5f);
#pragma unroll
    for (int c8 = 0; c8 < 8; ++c8) {
      bf16x8 pk;
#pragma unroll
      for (int j = 0; j < 8; ++j) {
        const int d = c8 * 8 + j;
        pk[j] = (__bf16)((x[d] - mu) * rstd * gamma[d] + beta[d]);
      }
      *(bf16x8*)(xlb + tid * 144 + c8 * 16) = pk;
    }
  } else {
    const bf16x8 z = {};
#pragma unroll
    for (int c8 = 0; c8 < 8; ++c8)
      *(bf16x8*)(xlb + tid * 144 + c8 * 16) = z;
  }
  __syncthreads();

  // ---- MFMA: wave w owns rows w*64..+64; C[row=cs][col=c], K=64 ----
  const int l = tid & 63, w = tid >> 6;
  const int lr = l & 15, lk = l >> 4;

  bf16x8 bfr[4][2];
#pragma unroll
  for (int fj = 0; fj < 4; ++fj)
#pragma unroll
    for (int kk = 0; kk < 2; ++kk)
      bfr[fj][kk] = *(const bf16x8*)(whb + (fj * 16 + lr) * 144 + (kk * 4 + lk) * 16);

  f32x4 acc[4][4];
#pragma unroll
  for (int i = 0; i < 4; ++i)
#pragma unroll
    for (int j = 0; j < 4; ++j) acc[i][j] = (f32x4){0.f, 0.f, 0.f, 0.f};

#pragma unroll
  for (int fi = 0; fi < 4; ++fi) {
    bf16x8 af[2];
#pragma unroll
    for (int kk = 0; kk < 2; ++kk)
      af[kk] = *(const bf16x8*)(xlb + (w * 64 + fi * 16 + lr) * 144 + (kk * 4 + lk) * 16);
#pragma unroll
    for (int fj = 0; fj < 4; ++fj)
#pragma unroll
      for (int kk = 0; kk < 2; ++kk)
        acc[fi][fj] = __builtin_amdgcn_mfma_f32_16x16x32_bf16(af[kk], bfr[fj][kk], acc[fi][fj], 0, 0, 0);
  }

  // ---- epilogue: a scaled by inv; packed 8B stores at compacted cs ----
  const float inv = invp[0];
#pragma unroll
  for (int fi = 0; fi < 4; ++fi) {
    const int sg = (hf << 8) + w * 64 + fi * 16 + lk * 4;
#pragma unroll
    for (int fj = 0; fj < 4; ++fj) {
      const int c = fj * 16 + lr;
      bf16x4 pk;
      if (fj < 2) {
#pragma unroll
        for (int r = 0; r < 4; ++r) pk[r] = (__bf16)(acc[fi][fj][r] * inv);
        *(bf16x4*)(at + ((size_t)cn * DH + c) * DS + sg) = pk;
      } else {
#pragma unroll
        for (int r = 0; r < 4; ++r) pk[r] = (__bf16)acc[fi][fj][r];
        *(bf16x4*)(bt + ((size_t)cn * DH + (c - 32)) * DS + sg) = pk;
      }
    }
  }
}

// ---------------------------------------------------------------------------
// fused (compacted): GEMM1 256x256 x K=64*nh (runtime), BK=64 dbuf, coarse
// loop; early-exit outside tiles x tiles. op->LDS -> GEMM2 (2-window wt
// pipeline) -> scatter epilogue via nperm (invalid pairs -> trash).
// ---------------------------------------------------------------------------
__global__ __launch_bounds__(512, 2) void fused_kernel(const __bf16* __restrict__ at,
                                                       const __bf16* __restrict__ bt,
                                                       const __bf16* __restrict__ wt,
                                                       const int* __restrict__ cnt,
                                                       const int* __restrict__ nperm,
                                                       const float* __restrict__ b_out,
                                                       float* __restrict__ trash,
                                                       float* __restrict__ out) {
  __shared__ __align__(128) char smem[132096];

  const int tid = threadIdx.x;
  const int l = tid & 63, w = tid >> 6;
  const int lr = l & 15, lk = l >> 4;
  const int wr = w >> 2, wc = w & 3;

  // XCD-aware swizzle: 48 supertiles of 8x6 blocks.
  const int orig = blockIdx.x;
  const int xcd = orig & 7, sidx = orig >> 3;
  const int stl = sidx / 48, u = sidx % 48;
  const int stg = xcd + stl * 8;
  const int stx = stg % 6, sty = stg / 6;
  const int bx = stx * 8 + (u & 7);
  const int by = sty * 6 + (u >> 3);

  const int scnt = cnt[0], ncnt = cnt[1];
  const int tiles = (ncnt + 7) >> 3;
  if (bx >= tiles || by >= tiles) return;
  int nh = (scnt + 63) >> 6;
  if (nh < 1) nh = 1;

  // staging source pointers (pre-swizzled: LDS[row][chl] <- logical chl^(row&7))
  const __bf16* gA[4];
  const __bf16* gB[4];
#pragma unroll
  for (int q = 0; q < 4; ++q) {
    const int idx = q * 512 + tid;
    const int row = idx >> 3, chl = idx & 7;
    const int src = (chl ^ (row & 7)) * 8;
    gA[q] = at + (size_t)(bx * 256 + row) * 512 + src;
    gB[q] = bt + (size_t)(by * 256 + row) * 512 + src;
  }

  f32x4 acc[8][4];
#pragma unroll
  for (int i = 0; i < 8; ++i)
#pragma unroll
    for (int j = 0; j < 4; ++j) acc[i][j] = (f32x4){0.f, 0.f, 0.f, 0.f};

  auto STAGE = [&](int h, int s) {
    char* da = smem + s * 65536 + tid * 16;
    char* db = da + 32768;
    const int go = h * 64;
#pragma unroll
    for (int q = 0; q < 4; ++q) {
      async16(gA[q] + go, da + q * 8192);
      async16(gB[q] + go, db + q * 8192);
    }
  };

  STAGE(0, 0);
  asm volatile("s_waitcnt vmcnt(0)" ::: "memory");
  __builtin_amdgcn_s_barrier();

  for (int h = 0; h < nh; ++h) {
    const char* A = smem + (h & 1) * 65536;
    const char* B = A + 32768;
    if (h + 1 < nh) STAGE(h + 1, (h + 1) & 1);

#pragma unroll
    for (int kk = 0; kk < 2; ++kk) {
      bf16x8 af[8], bfr[4];
      const int c = kk * 4 + lk;
      const int phys = (c ^ (lr & 7)) * 16;
#pragma unroll
      for (int fj = 0; fj < 4; ++fj) {
        const int r = wc * 64 + fj * 16 + lr;
        bfr[fj] = *(const bf16x8*)(B + r * 128 + phys);
      }
#pragma unroll
      for (int fi = 0; fi < 8; ++fi) {
        const int r = wr * 128 + fi * 16 + lr;
        af[fi] = *(const bf16x8*)(A + r * 128 + phys);
      }
#pragma unroll
      for (int fi = 0; fi < 8; ++fi)
#pragma unroll
        for (int fj = 0; fj < 4; ++fj)
          acc[fi][fj] = __builtin_amdgcn_mfma_f32_16x16x32_bf16(af[fi], bfr[fj], acc[fi][fj], 0, 0, 0);
    }

    if (h + 1 < nh) {
      asm volatile("s_waitcnt vmcnt(0)" ::: "memory");
      __builtin_amdgcn_s_barrier();
    }
  }

  asm volatile("" ::: "memory");
  __builtin_amdgcn_s_barrier();
  asm volatile("" ::: "memory");

  // ---- op tile -> LDS bf16 as A2[pair][k'=e*32+d], chunk-XOR swizzled ----
#pragma unroll
  for (int fi = 0; fi < 8; ++fi) {
    const int i_l = wr * 4 + (fi >> 1);
#pragma unroll
    for (int fj = 0; fj < 4; ++fj) {
      const int col = wc * 64 + fj * 16 + lr;
      const int j_l = col >> 5, e = col & 31;
      const int pair = i_l * 8 + j_l;
      const int cw = e * 4 + (fi & 1) * 2 + (lk >> 1);
      const int phys = cw ^ (e & 7);
      bf16x4 pk;
      pk[0] = (__bf16)acc[fi][fj][0];
      pk[1] = (__bf16)acc[fi][fj][1];
      pk[2] = (__bf16)acc[fi][fj][2];
      pk[3] = (__bf16)acc[fi][fj][3];
      *(bf16x4*)(smem + pair * 2064 + phys * 16 + (lk & 1) * 8) = pk;
    }
  }

  // GEMM2 geometry; issue window-0 wt loads before the drain barrier (T14)
  const int mf = w >> 2, pf = w & 3;
  const int l31 = l & 31, lh = l >> 5;
  const __bf16* wb = wt + (size_t)(pf * 32 + l31) * 16 + lh * 8;  // + kk*2048

  bf16x8 bw[8], bn[8];
#pragma unroll
  for (int j = 0; j < 8; ++j)
    bw[j] = *(const bf16x8*)(wb + (size_t)j * 2048);

  asm volatile("s_waitcnt lgkmcnt(0)" ::: "memory");
  __builtin_amdgcn_s_barrier();

  // ---- GEMM2: 2-window (8+8) pipelined, 32x32x16 MFMA ----
  f32x16 acc2v;
#pragma unroll
  for (int q = 0; q < 16; ++q) acc2v[q] = 0.f;

  const char* aBase = smem + (mf * 32 + l31) * 2064;
#pragma unroll
  for (int wnd = 0; wnd < 8; ++wnd) {
    if (wnd < 7) {
#pragma unroll
      for (int j = 0; j < 8; ++j)
        bn[j] = *(const bf16x8*)(wb + (size_t)((wnd + 1) * 8 + j) * 2048);
    }
#pragma unroll
    for (int j = 0; j < 8; ++j) {
      const int kk = wnd * 8 + j;
      const int cw = kk * 2 + lh;
      const int phys = cw ^ ((kk >> 1) & 7);
      const bf16x8 a2 = *(const bf16x8*)(aBase + phys * 16);
      acc2v = __builtin_amdgcn_mfma_f32_32x32x16_bf16(a2, bw[j], acc2v, 0, 0, 0);
    }
#pragma unroll
    for (int j = 0; j < 8; ++j) bw[j] = bn[j];
  }

  // ---- scatter epilogue: valid pairs -> out[nperm[ii]][nperm[jj]]; else trash ----
  const int p = pf * 32 + l31;
  const float bo = b_out[p];
#pragma unroll
  for (int reg = 0; reg < 16; ++reg) {
    const int pair = mf * 32 + (reg & 3) + 8 * (reg >> 2) + 4 * lh;
    const int ii = bx * 8 + (pair >> 3);
    const int jj = by * 8 + (pair & 7);
    const bool valid = (ii < ncnt) && (jj < ncnt);
    const int ig = nperm[ii];
    const int jg = nperm[jj];
    float* dst = valid ? (out + ((size_t)ig * DN + jg) * DP + p)
                       : (trash + (tid * 16 + reg));
    *dst = acc2v[reg] + bo;
  }
}

extern "C" void kernel_launch(void* const* d_in, const int* in_sizes, int n_in,
                              void* d_out, int out_size, void* d_ws, size_t ws_size,
                              hipStream_t stream) {
  const float* msa      = (const float*)d_in[0];
  const void*  mask     = d_in[1];
  const void*  msa_mask = d_in[2];
  const float* gamma    = (const float*)d_in[3];
  const float* beta     = (const float*)d_in[4];
  const float* w_hidden = (const float*)d_in[5];
  const float* w_out    = (const float*)d_in[6];
  const float* b_out    = (const float*)d_in[7];
  float* out = (float*)d_out;

  char* ws = (char*)d_ws;
  __bf16* at    = (__bf16*)ws;
  __bf16* bt    = (__bf16*)(ws + OFF_BT);
  __bf16* wt    = (__bf16*)(ws + OFF_WT);
  float*  inv   = (float*)(ws + OFF_INV);
  int*    cnt   = (int*)(ws + OFF_CNT);
  int*    sperm = (int*)(ws + OFF_SPERM);
  int*    nperm = (int*)(ws + OFF_NPERM);
  float*  trash = (float*)(ws + OFF_TRASH);

  prep_kernel<<<130, 128, 0, stream>>>(mask, msa_mask, w_out, wt, inv, cnt, sperm, nperm);
  fill_kernel<<<2304, 256, 0, stream>>>(b_out, out);
  ln_proj_kernel<<<768, 256, 0, stream>>>(msa, gamma, beta, w_hidden, inv, cnt, sperm, nperm, at, bt);
  fused_kernel<<<2304, 512, 0, stream>>>(at, bt, wt, cnt, nperm, b_out, trash, out);
}

// Round 13
// 78.197 us; speedup vs baseline: 5.3009x; 1.6399x over previous
//
#include <hip/hip_runtime.h>

#define DN 384
#define DS 512
#define DMSA 64
#define DH 32
#define DP 128

typedef __bf16 bf16x8 __attribute__((ext_vector_type(8)));
typedef __bf16 bf16x4 __attribute__((ext_vector_type(4)));
typedef float f32x4 __attribute__((ext_vector_type(4)));
typedef float f32x16 __attribute__((ext_vector_type(16)));

// ws layout (bytes)
#define OFF_BT    12582912u
#define OFF_WT    25165824u   // wt bf16 [kk 64][p 128][ks 16] = 256KB
#define OFF_INV   25427968u   // 1 f32
#define OFF_CNT   25428032u   // [scnt, ncnt]
#define OFF_SPERM 25428224u   // 512 i32
#define OFF_NPERM 25430272u   // 392 i32 (padded with 0)
#define OFF_TRASH 25432064u   // 32KB float trash for invalid-pair stores

__device__ __forceinline__ void async16(const void* g, void* l) {
  __builtin_amdgcn_global_load_lds((const __attribute__((address_space(1))) unsigned*)g,
                                   (__attribute__((address_space(3))) unsigned*)l, 16, 0, 0);
}

// ---------------------------------------------------------------------------
// prep: mask compaction (ballot-parallel) + w_out -> wt [kk][p][ks].
// ---------------------------------------------------------------------------
__global__ __launch_bounds__(128) void prep_kernel(const void* __restrict__ mask_raw,
                                                   const void* __restrict__ msa_mask_raw,
                                                   const float* __restrict__ w_out,
                                                   __bf16* __restrict__ wt,
                                                   float* __restrict__ invp,
                                                   int* __restrict__ cnt,
                                                   int* __restrict__ sperm,
                                                   int* __restrict__ nperm) {
  const int blk = blockIdx.x;
  const int tid = threadIdx.x;
  if (blk == 0) {
    // msa_mask: 512 elements -> sperm, scnt, inv
    __shared__ int sh[128];
    __shared__ float sv[512];
    __shared__ int sp[512];
    __shared__ int csh;
    const unsigned int* u = (const unsigned int*)msa_mask_raw;
    sh[tid] = (u[tid] > 1u) ? 1 : 0;   // first 128 ints = 512B, safe either dtype
    __syncthreads();
    for (int off = 64; off > 0; off >>= 1) {
      if (tid < off) sh[tid] |= sh[tid + off];
      __syncthreads();
    }
    const int int_mode = (sh[0] == 0);
    __syncthreads();
    for (int q = tid; q < DS; q += 128) {
      float v;
      if (int_mode) v = (((const int*)msa_mask_raw)[q] != 0) ? 1.f : 0.f;
      else          v = (((const unsigned char*)msa_mask_raw)[q] != 0) ? 1.f : 0.f;
      sv[q] = v;
    }
    __syncthreads();
    if (tid < 64) {
      int base = 0;
#pragma unroll
      for (int r = 0; r < 8; ++r) {
        const int s = r * 64 + tid;
        const bool v = (sv[s] != 0.f);
        const unsigned long long bal = __ballot(v);
        const int below = __popcll(bal & ((1ull << tid) - 1ull));
        if (v) sp[base + below] = s;
        base += __popcll(bal);
      }
      if (tid == 0) {
        csh = base;
        cnt[0] = base;
        float num = (float)base;
        if (num < 1e-5f) num = 1e-5f;
        invp[0] = 1.0f / num;
      }
    }
    __syncthreads();
    const int c = csh;
    for (int q = tid; q < c; q += 128) sperm[q] = sp[q];
  } else if (blk == 1) {
    // mask: 384 elements -> nperm (padded to 392 with 0), ncnt
    __shared__ int sh[128];
    __shared__ float sv[384];
    __shared__ int sp[384];
    __shared__ int csh;
    const unsigned int* u = (const unsigned int*)mask_raw;
    sh[tid] = (tid < 96) ? ((u[tid] > 1u) ? 1 : 0) : 0;
    __syncthreads();
    for (int off = 64; off > 0; off >>= 1) {
      if (tid < off) sh[tid] |= sh[tid + off];
      __syncthreads();
    }
    const int int_mode = (sh[0] == 0);
    __syncthreads();
    for (int q = tid; q < DN; q += 128) {
      float v;
      if (int_mode) v = (((const int*)mask_raw)[q] != 0) ? 1.f : 0.f;
      else          v = (((const unsigned char*)mask_raw)[q] != 0) ? 1.f : 0.f;
      sv[q] = v;
    }
    __syncthreads();
    if (tid < 64) {
      int base = 0;
#pragma unroll
      for (int r = 0; r < 6; ++r) {
        const int n = r * 64 + tid;
        const bool v = (sv[n] != 0.f);
        const unsigned long long bal = __ballot(v);
        const int below = __popcll(bal & ((1ull << tid) - 1ull));
        if (v) sp[base + below] = n;
        base += __popcll(bal);
      }
      if (tid == 0) {
        csh = base;
        cnt[1] = base;
      }
    }
    __syncthreads();
    const int c = csh;
    for (int q = tid; q < 392; q += 128) nperm[q] = (q < c) ? sp[q] : 0;
  } else {
    const int p = blk - 2;                        // 0..127
    const int kk = tid >> 1, ks0 = (tid & 1) * 8; // 16B run
    bf16x8 pk;
#pragma unroll
    for (int j = 0; j < 8; ++j) {
      const int kp = kk * 16 + ks0 + j;           // k' = e*32+d
      const int d = kp & 31, e = kp >> 5;
      pk[j] = (__bf16)w_out[(size_t)(d * 32 + e) * DP + p];
    }
    *(bf16x8*)(wt + ((size_t)kk * 128 + p) * 16 + ks0) = pk;
  }
}

// ---------------------------------------------------------------------------
// ln_proj v4: blocks b < 2*ntile8 do compacted LN+projection; the remaining
// blocks (>=64 always) stream b_out into out (fill), overlapped with LN work.
// ---------------------------------------------------------------------------
__global__ __launch_bounds__(256) void ln_proj_kernel(const float* __restrict__ msa,
                                                      const float* __restrict__ gamma,
                                                      const float* __restrict__ beta,
                                                      const float* __restrict__ w_hidden,
                                                      const float* __restrict__ invp,
                                                      const int* __restrict__ cnt,
                                                      const int* __restrict__ sperm,
                                                      const int* __restrict__ nperm,
                                                      const float* __restrict__ b_out,
                                                      float* __restrict__ out,
                                                      __bf16* __restrict__ at,
                                                      __bf16* __restrict__ bt) {
  __shared__ __align__(16) char lds[46080];
  char* xlb = lds;            // 256 rows x 144B (64 bf16 + 16B pad)
  char* whb = lds + 36864;    // 64 rows x 144B: wh[c][d] bf16

  const int tid = threadIdx.x;
  const int b = blockIdx.x;

  const int scnt = cnt[0], ncnt = cnt[1];
  const int ntile8 = ((ncnt + 7) >> 3) << 3;

  if (b >= 2 * ntile8) {
    // ---- fill worker: out[i][j][:] = b_out (valid pairs overwritten later) ----
    const int nW = 832 - 2 * ntile8;              // >= 64
    const int fi = b - 2 * ntile8;
    const float4 bv = ((const float4*)b_out)[tid & 31];  // invariant: 256 % 32 == 0
    float4* o4 = (float4*)out;
    const size_t total4 = (size_t)DN * DN * 32;
    for (size_t q = (size_t)fi * 256 + tid; q < total4; q += (size_t)nW * 256)
      o4[q] = bv;
    return;
  }

  const int cn = b >> 1;
  const int hf = b & 1;

  // stage w_hidden^T: wh[c][d] = w_hidden[d][c]
  for (int idx = tid; idx < 4096; idx += 256) {
    const int d = idx >> 6, c = idx & 63;
    *(__bf16*)(whb + c * 144 + d * 2) = (__bf16)w_hidden[idx];
  }

  const int cs = (hf << 8) + tid;
  const bool act = (cn < ncnt) && (cs < scnt);

  if (act) {
    const int n = nperm[cn];
    const int s = sperm[cs];
    const float* mp = msa + ((size_t)s * DN + n) * DMSA;
    float x[64];
    float sum = 0.f, sq = 0.f;
#pragma unroll
    for (int q = 0; q < 16; ++q) {
      float4 v = ((const float4*)mp)[q];
      x[4 * q + 0] = v.x; x[4 * q + 1] = v.y; x[4 * q + 2] = v.z; x[4 * q + 3] = v.w;
      sum += v.x + v.y + v.z + v.w;
      sq  += v.x * v.x + v.y * v.y + v.z * v.z + v.w * v.w;
    }
    const float mu = sum * (1.f / 64.f);
    const float var = sq * (1.f / 64.f) - mu * mu;
    const float rstd = rsqrtf(var + 1e-5f);
#pragma unroll
    for (int c8 = 0; c8 < 8; ++c8) {
      bf16x8 pk;
#pragma unroll
      for (int j = 0; j < 8; ++j) {
        const int d = c8 * 8 + j;
        pk[j] = (__bf16)((x[d] - mu) * rstd * gamma[d] + beta[d]);
      }
      *(bf16x8*)(xlb + tid * 144 + c8 * 16) = pk;
    }
  } else {
    const bf16x8 z = {};
#pragma unroll
    for (int c8 = 0; c8 < 8; ++c8)
      *(bf16x8*)(xlb + tid * 144 + c8 * 16) = z;
  }
  __syncthreads();

  // ---- MFMA: wave w owns rows w*64..+64; C[row=cs][col=c], K=64 ----
  const int l = tid & 63, w = tid >> 6;
  const int lr = l & 15, lk = l >> 4;

  bf16x8 bfr[4][2];
#pragma unroll
  for (int fj = 0; fj < 4; ++fj)
#pragma unroll
    for (int kk = 0; kk < 2; ++kk)
      bfr[fj][kk] = *(const bf16x8*)(whb + (fj * 16 + lr) * 144 + (kk * 4 + lk) * 16);

  f32x4 acc[4][4];
#pragma unroll
  for (int i = 0; i < 4; ++i)
#pragma unroll
    for (int j = 0; j < 4; ++j) acc[i][j] = (f32x4){0.f, 0.f, 0.f, 0.f};

#pragma unroll
  for (int fi = 0; fi < 4; ++fi) {
    bf16x8 af[2];
#pragma unroll
    for (int kk = 0; kk < 2; ++kk)
      af[kk] = *(const bf16x8*)(xlb + (w * 64 + fi * 16 + lr) * 144 + (kk * 4 + lk) * 16);
#pragma unroll
    for (int fj = 0; fj < 4; ++fj)
#pragma unroll
      for (int kk = 0; kk < 2; ++kk)
        acc[fi][fj] = __builtin_amdgcn_mfma_f32_16x16x32_bf16(af[kk], bfr[fj][kk], acc[fi][fj], 0, 0, 0);
  }

  // ---- epilogue: a scaled by inv; packed 8B stores at compacted cs ----
  const float inv = invp[0];
#pragma unroll
  for (int fi = 0; fi < 4; ++fi) {
    const int sg = (hf << 8) + w * 64 + fi * 16 + lk * 4;
#pragma unroll
    for (int fj = 0; fj < 4; ++fj) {
      const int c = fj * 16 + lr;
      bf16x4 pk;
      if (fj < 2) {
#pragma unroll
        for (int r = 0; r < 4; ++r) pk[r] = (__bf16)(acc[fi][fj][r] * inv);
        *(bf16x4*)(at + ((size_t)cn * DH + c) * DS + sg) = pk;
      } else {
#pragma unroll
        for (int r = 0; r < 4; ++r) pk[r] = (__bf16)acc[fi][fj][r];
        *(bf16x4*)(bt + ((size_t)cn * DH + (c - 32)) * DS + sg) = pk;
      }
    }
  }
}

// ---------------------------------------------------------------------------
// fused (compacted, actives-first): blocks orig < tiles^2 map via bijective
// XCD swizzle within the active square (m204); rest exit instantly. GEMM1
// 256x256 x K=64*nh coarse loop -> op->LDS -> GEMM2 (2-window wt pipeline)
// -> scatter epilogue via nperm (invalid pairs -> trash).
// ---------------------------------------------------------------------------
__global__ __launch_bounds__(512, 2) void fused_kernel(const __bf16* __restrict__ at,
                                                       const __bf16* __restrict__ bt,
                                                       const __bf16* __restrict__ wt,
                                                       const int* __restrict__ cnt,
                                                       const int* __restrict__ nperm,
                                                       const float* __restrict__ b_out,
                                                       float* __restrict__ trash,
                                                       float* __restrict__ out) {
  __shared__ __align__(128) char smem[132096];

  const int tid = threadIdx.x;
  const int l = tid & 63, w = tid >> 6;
  const int lr = l & 15, lk = l >> 4;
  const int wr = w >> 2, wc = w & 3;

  const int scnt = cnt[0], ncnt = cnt[1];
  const int tiles = (ncnt + 7) >> 3;
  const int nwg = tiles * tiles;
  const int orig = blockIdx.x;
  if (orig >= nwg) return;

  // bijective XCD swizzle within [0, nwg)
  const int xcd = orig & 7;
  const int qq = nwg >> 3, rr = nwg & 7;
  const int wgid = (xcd < rr ? xcd * (qq + 1) : rr * (qq + 1) + (xcd - rr) * qq) + (orig >> 3);
  const int bx = wgid % tiles;
  const int by = wgid / tiles;

  int nh = (scnt + 63) >> 6;
  if (nh < 1) nh = 1;

  // staging source pointers (pre-swizzled: LDS[row][chl] <- logical chl^(row&7))
  const __bf16* gA[4];
  const __bf16* gB[4];
#pragma unroll
  for (int q = 0; q < 4; ++q) {
    const int idx = q * 512 + tid;
    const int row = idx >> 3, chl = idx & 7;
    const int src = (chl ^ (row & 7)) * 8;
    gA[q] = at + (size_t)(bx * 256 + row) * 512 + src;
    gB[q] = bt + (size_t)(by * 256 + row) * 512 + src;
  }

  f32x4 acc[8][4];
#pragma unroll
  for (int i = 0; i < 8; ++i)
#pragma unroll
    for (int j = 0; j < 4; ++j) acc[i][j] = (f32x4){0.f, 0.f, 0.f, 0.f};

  auto STAGE = [&](int h, int s) {
    char* da = smem + s * 65536 + tid * 16;
    char* db = da + 32768;
    const int go = h * 64;
#pragma unroll
    for (int q = 0; q < 4; ++q) {
      async16(gA[q] + go, da + q * 8192);
      async16(gB[q] + go, db + q * 8192);
    }
  };

  STAGE(0, 0);
  asm volatile("s_waitcnt vmcnt(0)" ::: "memory");
  __builtin_amdgcn_s_barrier();

  for (int h = 0; h < nh; ++h) {
    const char* A = smem + (h & 1) * 65536;
    const char* B = A + 32768;
    if (h + 1 < nh) STAGE(h + 1, (h + 1) & 1);

#pragma unroll
    for (int kk = 0; kk < 2; ++kk) {
      bf16x8 af[8], bfr[4];
      const int c = kk * 4 + lk;
      const int phys = (c ^ (lr & 7)) * 16;
#pragma unroll
      for (int fj = 0; fj < 4; ++fj) {
        const int r = wc * 64 + fj * 16 + lr;
        bfr[fj] = *(const bf16x8*)(B + r * 128 + phys);
      }
#pragma unroll
      for (int fi = 0; fi < 8; ++fi) {
        const int r = wr * 128 + fi * 16 + lr;
        af[fi] = *(const bf16x8*)(A + r * 128 + phys);
      }
#pragma unroll
      for (int fi = 0; fi < 8; ++fi)
#pragma unroll
        for (int fj = 0; fj < 4; ++fj)
          acc[fi][fj] = __builtin_amdgcn_mfma_f32_16x16x32_bf16(af[fi], bfr[fj], acc[fi][fj], 0, 0, 0);
    }

    if (h + 1 < nh) {
      asm volatile("s_waitcnt vmcnt(0)" ::: "memory");
      __builtin_amdgcn_s_barrier();
    }
  }

  asm volatile("" ::: "memory");
  __builtin_amdgcn_s_barrier();
  asm volatile("" ::: "memory");

  // ---- op tile -> LDS bf16 as A2[pair][k'=e*32+d], chunk-XOR swizzled ----
#pragma unroll
  for (int fi = 0; fi < 8; ++fi) {
    const int i_l = wr * 4 + (fi >> 1);
#pragma unroll
    for (int fj = 0; fj < 4; ++fj) {
      const int col = wc * 64 + fj * 16 + lr;
      const int j_l = col >> 5, e = col & 31;
      const int pair = i_l * 8 + j_l;
      const int cw = e * 4 + (fi & 1) * 2 + (lk >> 1);
      const int phys = cw ^ (e & 7);
      bf16x4 pk;
      pk[0] = (__bf16)acc[fi][fj][0];
      pk[1] = (__bf16)acc[fi][fj][1];
      pk[2] = (__bf16)acc[fi][fj][2];
      pk[3] = (__bf16)acc[fi][fj][3];
      *(bf16x4*)(smem + pair * 2064 + phys * 16 + (lk & 1) * 8) = pk;
    }
  }

  // GEMM2 geometry; issue window-0 wt loads before the drain barrier (T14)
  const int mf = w >> 2, pf = w & 3;
  const int l31 = l & 31, lh = l >> 5;
  const __bf16* wb = wt + (size_t)(pf * 32 + l31) * 16 + lh * 8;  // + kk*2048

  bf16x8 bw[8], bn[8];
#pragma unroll
  for (int j = 0; j < 8; ++j)
    bw[j] = *(const bf16x8*)(wb + (size_t)j * 2048);

  asm volatile("s_waitcnt lgkmcnt(0)" ::: "memory");
  __builtin_amdgcn_s_barrier();

  // ---- GEMM2: 2-window (8+8) pipelined, 32x32x16 MFMA ----
  f32x16 acc2v;
#pragma unroll
  for (int q = 0; q < 16; ++q) acc2v[q] = 0.f;

  const char* aBase = smem + (mf * 32 + l31) * 2064;
#pragma unroll
  for (int wnd = 0; wnd < 8; ++wnd) {
    if (wnd < 7) {
#pragma unroll
      for (int j = 0; j < 8; ++j)
        bn[j] = *(const bf16x8*)(wb + (size_t)((wnd + 1) * 8 + j) * 2048);
    }
#pragma unroll
    for (int j = 0; j < 8; ++j) {
      const int kk = wnd * 8 + j;
      const int cw = kk * 2 + lh;
      const int phys = cw ^ ((kk >> 1) & 7);
      const bf16x8 a2 = *(const bf16x8*)(aBase + phys * 16);
      acc2v = __builtin_amdgcn_mfma_f32_32x32x16_bf16(a2, bw[j], acc2v, 0, 0, 0);
    }
#pragma unroll
    for (int j = 0; j < 8; ++j) bw[j] = bn[j];
  }

  // ---- scatter epilogue: valid pairs -> out[nperm[ii]][nperm[jj]]; else trash ----
  const int p = pf * 32 + l31;
  const float bo = b_out[p];
#pragma unroll
  for (int reg = 0; reg < 16; ++reg) {
    const int pair = mf * 32 + (reg & 3) + 8 * (reg >> 2) + 4 * lh;
    const int ii = bx * 8 + (pair >> 3);
    const int jj = by * 8 + (pair & 7);
    const bool valid = (ii < ncnt) && (jj < ncnt);
    const int ig = nperm[ii];
    const int jg = nperm[jj];
    float* dst = valid ? (out + ((size_t)ig * DN + jg) * DP + p)
                       : (trash + (tid * 16 + reg));
    *dst = acc2v[reg] + bo;
  }
}

extern "C" void kernel_launch(void* const* d_in, const int* in_sizes, int n_in,
                              void* d_out, int out_size, void* d_ws, size_t ws_size,
                              hipStream_t stream) {
  const float* msa      = (const float*)d_in[0];
  const void*  mask     = d_in[1];
  const void*  msa_mask = d_in[2];
  const float* gamma    = (const float*)d_in[3];
  const float* beta     = (const float*)d_in[4];
  const float* w_hidden = (const float*)d_in[5];
  const float* w_out    = (const float*)d_in[6];
  const float* b_out    = (const float*)d_in[7];
  float* out = (float*)d_out;

  char* ws = (char*)d_ws;
  __bf16* at    = (__bf16*)ws;
  __bf16* bt    = (__bf16*)(ws + OFF_BT);
  __bf16* wt    = (__bf16*)(ws + OFF_WT);
  float*  inv   = (float*)(ws + OFF_INV);
  int*    cnt   = (int*)(ws + OFF_CNT);
  int*    sperm = (int*)(ws + OFF_SPERM);
  int*    nperm = (int*)(ws + OFF_NPERM);
  float*  trash = (float*)(ws + OFF_TRASH);

  prep_kernel<<<130, 128, 0, stream>>>(mask, msa_mask, w_out, wt, inv, cnt, sperm, nperm);
  ln_proj_kernel<<<832, 256, 0, stream>>>(msa, gamma, beta, w_hidden, inv, cnt, sperm, nperm,
                                          b_out, out, at, bt);
  fused_kernel<<<2304, 512, 0, stream>>>(at, bt, wt, cnt, nperm, b_out, trash, out);
}